// Round 15
// baseline (457.978 us; speedup 1.0000x reference)
//
#include <hip/hip_runtime.h>

#define N_NODES 50000
#define NEDGE   800000
#define HID     128
#define LDSP    129          // doubles per LDS row (fp64 repair kernel)
#define TAU     2.5e-7       // flag margin: must exceed 1e-7 ref-slack + 2*dy
#define NPAD    50176        // node-padded leading dim for featT4 (mult of 256)
#define VROW    132          // padded vals row (floats) in edgeA layer-3

// ---- workspace layout (units: doubles) ----
#define W1D_OFF 0            // 257*128 = 32896, row-major [k][j]
#define B1D_OFF 32896        // 128
#define W2D_OFF 33024        // 128*128 = 16384
#define B2D_OFF 49408        // 128
#define W3D_OFF 49536        // 128
#define B3D_OFF 49664        // 1
#define NWCONV  49665
#define PQ64_OFF 49672                                        // P64,Q64: each N*128 doubles
#define P32_OFF_D   (PQ64_OFF + 2ull * N_NODES * HID)         // P32,Q32 floats overlay
#define FLAG_OFF_D  (P32_OFF_D + 1ull * N_NODES * HID)        // int cnt + int list[N]
#define W2FHI_OFF_D (FLAG_OFF_D + 25008)                      // W2 frag-order bf16 hi, 16384 shorts
#define W2FLO_OFF_D (W2FHI_OFF_D + 4096)
#define FEATT_OFF_D (W2FLO_OFF_D + 4096)                      // featT4: 32*NPAD float4
// total ~180 MB < 256 MiB workspace

typedef __attribute__((ext_vector_type(8)))  short short8;
typedef __attribute__((ext_vector_type(16))) float f32x16;

__device__ __forceinline__ unsigned short f2bf(float f) {
    const unsigned u = __float_as_uint(f);
    const unsigned r = u + 0x7FFFu + ((u >> 16) & 1u);   // RN-even; inputs finite
    return (unsigned short)(r >> 16);
}
__device__ __forceinline__ float bf2f(unsigned short h) {
    return __uint_as_float((unsigned)h << 16);
}

// ---------------------------------------------------------------------------
// Kernel 0: weights to fp64 + W2 bf16 hi/lo in MFMA fragment order (round-8
// verified); zero the flagged-node counter.
// ---------------------------------------------------------------------------
__global__ void conv_kernel(const float* __restrict__ w1, const float* __restrict__ b1,
                            const float* __restrict__ w2, const float* __restrict__ b2,
                            const float* __restrict__ w3, const float* __restrict__ b3,
                            double* __restrict__ wsd) {
    const int i = blockIdx.x * 256 + threadIdx.x;
    if (i == 0) *(int*)(wsd + FLAG_OFF_D) = 0;
    if (i < 16384) {                       // W2 frag split
        const int c  = i & 7;
        const int l  = (i >> 3) & 63;
        const int jt = (i >> 9) & 3;
        const int s  = i >> 11;
        const int jj = jt * 32 + (l & 31);
        const int k  = s * 16 + (l >> 5) * 8 + c;
        const float v = w2[k * 128 + jj];
        const unsigned short hi = f2bf(v);
        const unsigned short lo = f2bf(v - bf2f(hi));
        ((short*)(wsd + W2FHI_OFF_D))[i] = (short)hi;
        ((short*)(wsd + W2FLO_OFF_D))[i] = (short)lo;
    }
    if (i >= NWCONV) return;
    float v;
    if      (i < B1D_OFF) v = w1[i];
    else if (i < W2D_OFF) v = b1[i - B1D_OFF];
    else if (i < B2D_OFF) v = w2[i - W2D_OFF];
    else if (i < W3D_OFF) v = b2[i - B2D_OFF];
    else if (i < B3D_OFF) v = w3[i - W3D_OFF];
    else                  v = b3[0];
    wsd[i] = (double)v;
}

// ---------------------------------------------------------------------------
// Kernel 0b: features [N][128] -> featT4 [kb][n] float4 (kb = k/4); rows
// [N_NODES, NPAD) zero-filled so padded pq blocks read clean zeros.
// ---------------------------------------------------------------------------
__global__ __launch_bounds__(512, 2)
void trans_kernel(const float* __restrict__ features, float* __restrict__ featT4) {
    __shared__ float fts[64 * 132];
    const int t  = threadIdx.x;
    const int n0 = blockIdx.x * 64;

    {   // coalesced row loads: n = t>>3, 16 floats per thread
        const int n = t >> 3, c0 = (t & 7) * 16;
        const int gn = n0 + n;
        #pragma unroll
        for (int i = 0; i < 4; ++i) {
            float4 f = make_float4(0.f, 0.f, 0.f, 0.f);
            if (gn < N_NODES) f = *(const float4*)(features + (size_t)gn * HID + c0 + i * 4);
            *(float4*)(&fts[n * 132 + c0 + i * 4]) = f;
        }
    }
    __syncthreads();

    {   // coalesced column-block stores: lane = n, kb = (t>>6) + i*8
        const int n = t & 63;
        #pragma unroll
        for (int i = 0; i < 4; ++i) {
            const int kb = (t >> 6) + i * 8;
            const float4 f = *(const float4*)(&fts[n * 132 + kb * 4]);
            *(float4*)(featT4 + ((size_t)kb * NPAD + n0 + n) * 4) = f;
        }
    }
}

// ---------------------------------------------------------------------------
// Kernel 1: P/Q fp64 GEMM.  W1-half staged in LDS (128 KB, fp64) + 4 NODES
// PER LANE: per k-step a wave issues 8 uniform ds_read_b128 (~48 cyc) that
// feed 64 v_fma_f64 wave-insts (~256 cyc) -- LDS broadcast amortized 4x vs
// round-10's 64-node version (which was LDS-issue-bound), and the s_load
// latency chain of rounds 11-14 (~140us) is gone entirely.  fma chain
// (k-ascending), operand values, and write pattern BIT-IDENTICAL to the
// round-14-verified pq -> absmax 0.0 structurally guaranteed.
// ---------------------------------------------------------------------------
__global__ __launch_bounds__(512, 1)
void pq_kernel(const float* __restrict__ featT4,
               const double* __restrict__ wsd,
               double* __restrict__ P,
               double* __restrict__ Q,
               float* __restrict__ P32,
               float* __restrict__ Q32) {
    __shared__ double w1s[128 * 128];            // 128 KB: W1 half, [k][j]
    const int t   = threadIdx.x;
    const int n0  = blockIdx.x * 256;            // 256 nodes per block
    const int sel = blockIdx.y;

    {   // stage W1 half from wsd (fp64, L2-hot): 16 double2 per thread
        const double2* src = (const double2*)(wsd + W1D_OFF + (size_t)(sel * 128) * HID);
        double2* dst = (double2*)w1s;
        #pragma unroll
        for (int i = 0; i < 16; ++i)
            dst[t + i * 512] = src[t + i * 512];
    }
    __syncthreads();

    const int l  = t & 63;
    const int wv = __builtin_amdgcn_readfirstlane(t >> 6);
    const int j0 = wv * 16;
    const double* wb = w1s + j0;

    double a0[16], a1[16], a2[16], a3[16];
    #pragma unroll
    for (int c = 0; c < 16; ++c) { a0[c] = 0.0; a1[c] = 0.0; a2[c] = 0.0; a3[c] = 0.0; }

    const float4* fbase = (const float4*)featT4;
    #pragma unroll 2
    for (int kb = 0; kb < 32; ++kb) {
        const size_t rb = (size_t)kb * NPAD + n0 + l;
        const float4 f0 = fbase[rb];
        const float4 f1 = fbase[rb + 64];
        const float4 f2 = fbase[rb + 128];
        const float4 f3 = fbase[rb + 192];
        #pragma unroll
        for (int j = 0; j < 4; ++j) {
            const double* wr = wb + (size_t)(kb * 4 + j) * 128;    // uniform -> broadcast
            const double v0 = (double)((&f0.x)[j]);
            const double v1 = (double)((&f1.x)[j]);
            const double v2 = (double)((&f2.x)[j]);
            const double v3 = (double)((&f3.x)[j]);
            #pragma unroll
            for (int c = 0; c < 16; ++c) {
                const double w = wr[c];
                a0[c] = fma(v0, w, a0[c]);
                a1[c] = fma(v1, w, a1[c]);
                a2[c] = fma(v2, w, a2[c]);
                a3[c] = fma(v3, w, a3[c]);
            }
        }
    }

    double* dstD = (sel ? Q : P);
    float*  dstF = (sel ? Q32 : P32);
    #pragma unroll
    for (int i = 0; i < 4; ++i) {
        const int gn = n0 + i * 64 + l;
        if (gn >= N_NODES) continue;
        const double* ai = (i == 0) ? a0 : (i == 1) ? a1 : (i == 2) ? a2 : a3;
        double* dst = dstD + (size_t)gn * HID + j0;
        #pragma unroll
        for (int c = 0; c < 16; c += 2)
            *(double2*)(dst + c) = make_double2(ai[c], ai[c + 1]);
        float* dstf = dstF + (size_t)gn * HID + j0;
        #pragma unroll
        for (int c = 0; c < 16; c += 4)
            *(float4*)(dstf + c) = make_float4((float)ai[c], (float)ai[c + 1],
                                               (float)ai[c + 2], (float)ai[c + 3]);
    }
}

// ---------------------------------------------------------------------------
// Kernel 2 (pass A, FUSED): layer-1 fp32 -> h1 bf16 hi/lo (swizzled LDS) ->
// layer-2 bf16x3 MFMA -> layer-3 via padded LDS transpose -> exact-order z
// (fp64 sum of 8 fp32 quarters) -> inline fp64 epilogue on wave 0.
// (round-14 verified, unchanged)
// ---------------------------------------------------------------------------
__global__ __launch_bounds__(512, 4)
void edgeA_kernel(const int*   __restrict__ indices,
                  const float* __restrict__ values,
                  const float* __restrict__ P32,
                  const float* __restrict__ Q32,
                  const float* __restrict__ w1,
                  const float* __restrict__ b1,
                  const short* __restrict__ w2fhi,
                  const short* __restrict__ w2flo,
                  const float* __restrict__ b2,
                  const float* __restrict__ w3,
                  const float* __restrict__ b3,
                  const float* __restrict__ tempr,
                  int*         __restrict__ fcnt,
                  int*         __restrict__ flist,
                  float*       __restrict__ out) {
    __shared__ __align__(16) char smemA[64 * VROW * 4];  // h1 hi|lo ; later vals[64][132]
    __shared__ float zpartS[8][64];
    float* vals = (float*)smemA;

    const int t  = threadIdx.x;
    const int e0 = blockIdx.x * 64;

    // ---- stage h1: fp32 layer-1, split to bf16 hi/lo, swizzled LDS ----
    {
        const int e = t & 63, q = t >> 6;
        const int ge  = e0 + e;
        const int row = indices[ge];
        const int col = indices[NEDGE + ge];
        const float v = values[ge];
        const float* prow = P32 + (size_t)row * HID + q * 16;
        const float* qrow = Q32 + (size_t)col * HID + q * 16;
        const float* w1c  = w1 + (size_t)256 * HID + q * 16;  // uniform -> s_load
        const float* b1f  = b1 + q * 16;
        float h[16];
        #pragma unroll
        for (int i = 0; i < 16; i += 4) {
            float4 p  = *(const float4*)(prow + i);
            float4 qq = *(const float4*)(qrow + i);
            h[i]     = fmaxf(fmaf(v, w1c[i],     p.x + qq.x) + b1f[i],     0.f);
            h[i + 1] = fmaxf(fmaf(v, w1c[i + 1], p.y + qq.y) + b1f[i + 1], 0.f);
            h[i + 2] = fmaxf(fmaf(v, w1c[i + 2], p.z + qq.z) + b1f[i + 2], 0.f);
            h[i + 3] = fmaxf(fmaf(v, w1c[i + 3], p.w + qq.w) + b1f[i + 3], 0.f);
        }
        union { short s[8]; short8 v8; } H0, H1, L0, L1;
        #pragma unroll
        for (int i = 0; i < 8; ++i) {
            const unsigned short hiA = f2bf(h[i]);
            H0.s[i] = (short)hiA;
            L0.s[i] = (short)f2bf(h[i] - bf2f(hiA));
            const unsigned short hiB = f2bf(h[i + 8]);
            H1.s[i] = (short)hiB;
            L1.s[i] = (short)f2bf(h[i + 8] - bf2f(hiB));
        }
        const int a0 = (e * 256 + q * 32) ^ ((e & 7) << 4);
        *(short8*)(smemA + a0)                = H0.v8;
        *(short8*)(smemA + (a0 ^ 16))         = H1.v8;
        *(short8*)(smemA + 16384 + a0)        = L0.v8;
        *(short8*)(smemA + 16384 + (a0 ^ 16)) = L1.v8;
    }
    __syncthreads();

    // ---- layer-2: bf16x3 MFMA, one 32x32 tile per wave, K = 8x16 ----
    const int l  = t & 63;
    const int wv = __builtin_amdgcn_readfirstlane(t >> 6);
    const int jt = wv & 3, et = wv >> 2;
    const int jj = jt * 32 + (l & 31);
    const short* w2h_l = w2fhi + (size_t)(jt * 64 + l) * 8;
    const short* w2l_l = w2flo + (size_t)(jt * 64 + l) * 8;

    f32x16 acc;
    #pragma unroll
    for (int r = 0; r < 16; ++r) acc[r] = 0.f;
    const int eA    = et * 32 + (l & 31);
    const int abase = eA * 256;
    const int aswz  = (eA & 7) << 4;
    const int ah    = (l >> 5) * 16;
    #pragma unroll 2
    for (int s = 0; s < 8; ++s) {
        const int ao = (abase + s * 32 + ah) ^ aswz;
        const short8 ahi = *(const short8*)(smemA + ao);
        const short8 alo = *(const short8*)(smemA + 16384 + ao);
        const short8 bh  = *(const short8*)(w2h_l + s * 2048);
        const short8 bl  = *(const short8*)(w2l_l + s * 2048);
        acc = __builtin_amdgcn_mfma_f32_32x32x16_bf16(ahi, bh, acc, 0, 0, 0);
        acc = __builtin_amdgcn_mfma_f32_32x32x16_bf16(alo, bh, acc, 0, 0, 0);
        acc = __builtin_amdgcn_mfma_f32_32x32x16_bf16(ahi, bl, acc, 0, 0, 0);
    }
    __syncthreads();   // all waves done reading h1 -> safe to overwrite as vals

    // ---- layer-3 part 1: write relu(acc+b2)*w3 to padded vals[64][132] ----
    {
        const float b2j = b2[jj];
        const float w3j = w3[jj];
        #pragma unroll
        for (int r = 0; r < 16; ++r) {
            const int e_loc = (r & 3) + 8 * (r >> 2) + 4 * (l >> 5);
            const int e = et * 32 + e_loc;
            vals[e * VROW + jj] = fmaxf(acc[r] + b2j, 0.f) * w3j;
        }
    }
    __syncthreads();

    // ---- layer-3 part 2: per-thread serial sum of 16 j's (one quarter) ----
    {
        const int e = t & 63, q = t >> 6;
        float sq = 0.f;
        #pragma unroll
        for (int i = 0; i < 4; ++i) {
            const float4 v4 = *(const float4*)(vals + e * VROW + q * 16 + i * 4);
            sq += v4.x; sq += v4.y; sq += v4.z; sq += v4.w;   // jj ascending
        }
        zpartS[q][e] = sq;
    }
    __syncthreads();

    // ---- fused fp64 epilogue: 4 nodes x 16 edges on wave 0 ----
    if (t < 64) {
        double z = (double)b3[0];
        #pragma unroll
        for (int q = 0; q < 8; ++q) z += (double)zpartS[q][t];

        const double T = (double)tempr[0];
        const int base = t & 48;

        // softmax #1
        double m = z;
        #pragma unroll
        for (int d = 1; d < 16; d <<= 1) m = fmax(m, __shfl_xor(m, d));
        const double e1 = exp(z - m);
        double s = 0.0;
        #pragma unroll
        for (int k = 0; k < 16; ++k) s += __shfl(e1, base + k);
        const double pi = e1 / s;

        // hard-concrete, eval path
        const double x  = log(pi + 1e-8) / T;
        double hard = 1.0 / (1.0 + exp(-x));
        hard = fmin(fmax(hard, 0.0), 1.0);

        // softmax #2
        double m2 = hard;
        #pragma unroll
        for (int d = 1; d < 16; d <<= 1) m2 = fmax(m2, __shfl_xor(m2, d));
        const double e2 = exp(hard - m2);
        double s2 = 0.0;
        #pragma unroll
        for (int k = 0; k < 16; ++k) s2 += __shfl(e2, base + k);
        const double y = e2 / s2;

        // rank-8 threshold
        int cgt = 0, ceq = 0;
        #pragma unroll
        for (int j = 0; j < 16; ++j) {
            const double yj = __shfl(y, base + j);
            cgt += (yj > y);
            ceq += (yj == y);
        }
        double cand = (cgt <= 7 && cgt + ceq >= 8) ? y : -1.0e300;
        double thre = cand;
        #pragma unroll
        for (int d = 1; d < 16; d <<= 1) thre = fmax(thre, __shfl_xor(thre, d));

        const double g = (y - thre) + 1e-7;
        out[e0 + t] = (g > 0.0) ? (float)y : 0.0f;

        const bool near = (y != thre) && (fabs(g) < TAU);
        const unsigned long long ball = __ballot(near);
        if ((t & 15) == 0) {
            if ((ball >> base) & 0xFFFFull) {
                const int nid = (e0 >> 4) + (t >> 4);
                const int idx = atomicAdd(fcnt, 1);
                flist[idx] = nid;
            }
        }
    }
}

// ---------------------------------------------------------------------------
// Kernel 3 (pass B): exact fp64 pipeline for flagged nodes, P64/Q64-based
// (round-8 verified version).
// ---------------------------------------------------------------------------
__global__ __launch_bounds__(512, 4)
void edgeB_kernel(const int*   __restrict__ indices,
                  const float* __restrict__ values,
                  const float* __restrict__ tempr,
                  const double* __restrict__ wsd,
                  const double* __restrict__ P,
                  const double* __restrict__ Q,
                  const int*   __restrict__ fcnt,
                  const int*   __restrict__ flist,
                  float* __restrict__ out) {
    __shared__ double h1s[64 * LDSP];
    __shared__ double zpart[8][64];
    __shared__ int nids[4];
    const int t = threadIdx.x;
    const int cnt = *fcnt;

    for (int g0 = blockIdx.x * 4; g0 < cnt; g0 += gridDim.x * 4) {
        if (t < 4) nids[t] = (g0 + t < cnt) ? flist[g0 + t] : -1;
        __syncthreads();

        {
            const int e = t & 63, q = t >> 6;
            const int node = nids[e >> 4];
            double* hdst = &h1s[e * LDSP + q * 16];
            if (node >= 0) {
                const int ge = node * 16 + (e & 15);
                const int row = indices[ge];
                const int col = indices[NEDGE + ge];
                const double v = (double)values[ge];
                const double* prow = P + (size_t)row * HID + q * 16;
                const double* qrow = Q + (size_t)col * HID + q * 16;
                const double* w1c  = wsd + W1D_OFF + (size_t)256 * HID + q * 16;
                const double* b1d  = wsd + B1D_OFF + q * 16;
                #pragma unroll
                for (int i = 0; i < 16; i += 2) {
                    double2 p  = *(const double2*)(prow + i);
                    double2 qq = *(const double2*)(qrow + i);
                    hdst[i]     = fmax(fma(v, w1c[i],     p.x + qq.x) + b1d[i],     0.0);
                    hdst[i + 1] = fmax(fma(v, w1c[i + 1], p.y + qq.y) + b1d[i + 1], 0.0);
                }
            } else {
                #pragma unroll
                for (int i = 0; i < 16; ++i) hdst[i] = 0.0;
            }
        }
        __syncthreads();

        const int l  = t & 63;
        const int wv = __builtin_amdgcn_readfirstlane(t >> 6);
        const int j0 = wv * 16;
        const double* w2b = wsd + W2D_OFF + j0;

        double acc[16];
        #pragma unroll
        for (int c = 0; c < 16; ++c) acc[c] = 0.0;

        const double* hrow = &h1s[l * LDSP];
        for (int k = 0; k < 128; k += 2) {
            const double h0  = hrow[k];
            const double h1v = hrow[k + 1];
            const double* wr0 = w2b + (size_t)k * HID;
            const double* wr1 = wr0 + HID;
            #pragma unroll
            for (int c = 0; c < 16; ++c) acc[c] = fma(h0,  wr0[c], acc[c]);
            #pragma unroll
            for (int c = 0; c < 16; ++c) acc[c] = fma(h1v, wr1[c], acc[c]);
        }

        {
            const double* b2d = wsd + B2D_OFF + j0;
            const double* w3d = wsd + W3D_OFF + j0;
            double part = 0.0;
            #pragma unroll
            for (int c = 0; c < 16; ++c) {
                const double h2 = fmax(acc[c] + b2d[c], 0.0);
                part = fma(h2, w3d[c], part);
            }
            zpart[wv][l] = part;
        }
        __syncthreads();

        if (t < 64) {
            double z = wsd[B3D_OFF];
            #pragma unroll
            for (int w = 0; w < 8; ++w) z += zpart[w][t];

            const double T = (double)tempr[0];
            const int base = t & 48;

            double m = z;
            #pragma unroll
            for (int d = 1; d < 16; d <<= 1) m = fmax(m, __shfl_xor(m, d));
            const double e1 = exp(z - m);
            double s = 0.0;
            #pragma unroll
            for (int k = 0; k < 16; ++k) s += __shfl(e1, base + k);
            const double pi = e1 / s;

            const double x  = log(pi + 1e-8) / T;
            double hard = 1.0 / (1.0 + exp(-x));
            hard = fmin(fmax(hard, 0.0), 1.0);

            double m2 = hard;
            #pragma unroll
            for (int d = 1; d < 16; d <<= 1) m2 = fmax(m2, __shfl_xor(m2, d));
            const double e2 = exp(hard - m2);
            double s2 = 0.0;
            #pragma unroll
            for (int k = 0; k < 16; ++k) s2 += __shfl(e2, base + k);
            const double y = e2 / s2;

            int cgt = 0, ceq = 0;
            #pragma unroll
            for (int j = 0; j < 16; ++j) {
                const double yj = __shfl(y, base + j);
                cgt += (yj > y);
                ceq += (yj == y);
            }
            double cand = (cgt <= 7 && cgt + ceq >= 8) ? y : -1.0e300;
            double thre = cand;
            #pragma unroll
            for (int d = 1; d < 16; d <<= 1) thre = fmax(thre, __shfl_xor(thre, d));

            const double g = (y - thre) + 1e-7;
            const int node = nids[t >> 4];
            if (node >= 0)
                out[node * 16 + (t & 15)] = (g > 0.0) ? (float)y : 0.0f;
        }
        __syncthreads();
    }
}

// ---------------------------------------------------------------------------
extern "C" void kernel_launch(void* const* d_in, const int* in_sizes, int n_in,
                              void* d_out, int out_size, void* d_ws, size_t ws_size,
                              hipStream_t stream) {
    const float* features = (const float*)d_in[0];
    const int*   indices  = (const int*)  d_in[1];
    const float* values   = (const float*)d_in[2];
    const float* tempr    = (const float*)d_in[3];
    const float* w1       = (const float*)d_in[4];
    const float* b1       = (const float*)d_in[5];
    const float* w2       = (const float*)d_in[6];
    const float* b2       = (const float*)d_in[7];
    const float* w3       = (const float*)d_in[8];
    const float* b3       = (const float*)d_in[9];
    float* out = (float*)d_out;

    double* wsd = (double*)d_ws;
    double* P64 = wsd + PQ64_OFF;
    double* Q64 = P64 + (size_t)N_NODES * HID;
    float*  P32 = (float*)(wsd + P32_OFF_D);
    float*  Q32 = P32 + (size_t)N_NODES * HID;
    int*    fcnt  = (int*)(wsd + FLAG_OFF_D);
    int*    flist = fcnt + 1;
    const short* w2fhi = (const short*)(wsd + W2FHI_OFF_D);
    const short* w2flo = (const short*)(wsd + W2FLO_OFF_D);
    float* featT4 = (float*)(wsd + FEATT_OFF_D);

    conv_kernel<<<(NWCONV + 255) / 256, 256, 0, stream>>>(w1, b1, w2, b2, w3, b3, wsd);

    trans_kernel<<<NPAD / 64, 512, 0, stream>>>(features, featT4);

    dim3 g1((N_NODES + 255) / 256, 2);
    pq_kernel<<<g1, 512, 0, stream>>>(featT4, wsd, P64, Q64, P32, Q32);

    edgeA_kernel<<<NEDGE / 64, 512, 0, stream>>>(indices, values, P32, Q32,
                                                 w1, b1, w2fhi, w2flo, b2, w3, b3,
                                                 tempr, fcnt, flist, out);

    edgeB_kernel<<<512, 512, 0, stream>>>(indices, values, tempr, wsd, P64, Q64,
                                          fcnt, flist, out);
}

// Round 16
// 449.833 us; speedup vs baseline: 1.0181x; 1.0181x over previous
//
#include <hip/hip_runtime.h>

#define N_NODES 50000
#define NEDGE   800000
#define HID     128
#define LDSP    129          // doubles per LDS row (fp64 repair kernel)
#define TAU     1.5e-7       // flag margin: covers sign-flip (|g|<=2dy~4e-9) and
                             // rank-8/9 swap (|g|<=1e-7+4e-9), 23x margin over
                             // measured dy<=2e-9.  Was 2.5e-7; window x0.6.
#define NPAD    50176        // node-padded leading dim for featT4 (mult of 256)
#define VROW    132          // padded vals row (floats) in edgeA layer-3

// ---- workspace layout (units: doubles) ----
#define W1D_OFF 0            // 257*128 = 32896, row-major [k][j]
#define B1D_OFF 32896        // 128
#define W2D_OFF 33024        // 128*128 = 16384
#define B2D_OFF 49408        // 128
#define W3D_OFF 49536        // 128
#define B3D_OFF 49664        // 1
#define NWCONV  49665
#define PQ64_OFF 49672                                        // P64,Q64: each N*128 doubles
#define P32_OFF_D   (PQ64_OFF + 2ull * N_NODES * HID)         // P32,Q32 floats overlay
#define FLAG_OFF_D  (P32_OFF_D + 1ull * N_NODES * HID)        // int cnt + int list[N]
#define W2FHI_OFF_D (FLAG_OFF_D + 25008)                      // W2 frag-order bf16 hi, 16384 shorts
#define W2FLO_OFF_D (W2FHI_OFF_D + 4096)
#define FEATT_OFF_D (W2FLO_OFF_D + 4096)                      // featT4: 32*NPAD float4
// total ~180 MB < 256 MiB workspace

typedef __attribute__((ext_vector_type(8)))  short short8;
typedef __attribute__((ext_vector_type(16))) float f32x16;

__device__ __forceinline__ unsigned short f2bf(float f) {
    const unsigned u = __float_as_uint(f);
    const unsigned r = u + 0x7FFFu + ((u >> 16) & 1u);   // RN-even; inputs finite
    return (unsigned short)(r >> 16);
}
__device__ __forceinline__ float bf2f(unsigned short h) {
    return __uint_as_float((unsigned)h << 16);
}

// ---------------------------------------------------------------------------
// Kernel 0: weights to fp64 + W2 bf16 hi/lo in MFMA fragment order (round-8
// verified); zero the flagged-node counter.
// ---------------------------------------------------------------------------
__global__ void conv_kernel(const float* __restrict__ w1, const float* __restrict__ b1,
                            const float* __restrict__ w2, const float* __restrict__ b2,
                            const float* __restrict__ w3, const float* __restrict__ b3,
                            double* __restrict__ wsd) {
    const int i = blockIdx.x * 256 + threadIdx.x;
    if (i == 0) *(int*)(wsd + FLAG_OFF_D) = 0;
    if (i < 16384) {                       // W2 frag split
        const int c  = i & 7;
        const int l  = (i >> 3) & 63;
        const int jt = (i >> 9) & 3;
        const int s  = i >> 11;
        const int jj = jt * 32 + (l & 31);
        const int k  = s * 16 + (l >> 5) * 8 + c;
        const float v = w2[k * 128 + jj];
        const unsigned short hi = f2bf(v);
        const unsigned short lo = f2bf(v - bf2f(hi));
        ((short*)(wsd + W2FHI_OFF_D))[i] = (short)hi;
        ((short*)(wsd + W2FLO_OFF_D))[i] = (short)lo;
    }
    if (i >= NWCONV) return;
    float v;
    if      (i < B1D_OFF) v = w1[i];
    else if (i < W2D_OFF) v = b1[i - B1D_OFF];
    else if (i < B2D_OFF) v = w2[i - W2D_OFF];
    else if (i < W3D_OFF) v = b2[i - B2D_OFF];
    else if (i < B3D_OFF) v = w3[i - W3D_OFF];
    else                  v = b3[0];
    wsd[i] = (double)v;
}

// ---------------------------------------------------------------------------
// Kernel 0b: features [N][128] -> featT4 [kb][n] float4 (kb = k/4); rows
// [N_NODES, NPAD) zero-filled so padded pq blocks read clean zeros.
// ---------------------------------------------------------------------------
__global__ __launch_bounds__(512, 2)
void trans_kernel(const float* __restrict__ features, float* __restrict__ featT4) {
    __shared__ float fts[64 * 132];
    const int t  = threadIdx.x;
    const int n0 = blockIdx.x * 64;

    {   // coalesced row loads: n = t>>3, 16 floats per thread
        const int n = t >> 3, c0 = (t & 7) * 16;
        const int gn = n0 + n;
        #pragma unroll
        for (int i = 0; i < 4; ++i) {
            float4 f = make_float4(0.f, 0.f, 0.f, 0.f);
            if (gn < N_NODES) f = *(const float4*)(features + (size_t)gn * HID + c0 + i * 4);
            *(float4*)(&fts[n * 132 + c0 + i * 4]) = f;
        }
    }
    __syncthreads();

    {   // coalesced column-block stores: lane = n, kb = (t>>6) + i*8
        const int n = t & 63;
        #pragma unroll
        for (int i = 0; i < 4; ++i) {
            const int kb = (t >> 6) + i * 8;
            const float4 f = *(const float4*)(&fts[n * 132 + kb * 4]);
            *(float4*)(featT4 + ((size_t)kb * NPAD + n0 + n) * 4) = f;
        }
    }
}

// ---------------------------------------------------------------------------
// Kernel 1: P/Q fp64 GEMM, W1 via wave-uniform s_load, 4 nodes per lane
// (round-14 VERIFIED version, absmax 0.0, best measured total).  Round-15's
// LDS-staged variant was neutral -- reverted to the verified baseline.
// fma chain (k-ascending) bit-identical to rounds 8-15.
// ---------------------------------------------------------------------------
__global__ __launch_bounds__(512, 2)
void pq_kernel(const float* __restrict__ featT4,
               const double* __restrict__ wsd,
               double* __restrict__ P,
               double* __restrict__ Q,
               float* __restrict__ P32,
               float* __restrict__ Q32) {
    const int t   = threadIdx.x;
    const int n0  = blockIdx.x * 256;            // 256 nodes per block
    const int sel = blockIdx.y;
    const int l   = t & 63;
    const int wv  = __builtin_amdgcn_readfirstlane(t >> 6);
    const int j0  = wv * 16;
    const double* wb = wsd + W1D_OFF + (size_t)(sel * 128) * HID + j0;  // uniform

    double a0[16], a1[16], a2[16], a3[16];
    #pragma unroll
    for (int c = 0; c < 16; ++c) { a0[c] = 0.0; a1[c] = 0.0; a2[c] = 0.0; a3[c] = 0.0; }

    const float4* fbase = (const float4*)featT4;
    #pragma unroll 2
    for (int kb = 0; kb < 32; ++kb) {
        const size_t rb = (size_t)kb * NPAD + n0 + l;
        const float4 f0 = fbase[rb];
        const float4 f1 = fbase[rb + 64];
        const float4 f2 = fbase[rb + 128];
        const float4 f3 = fbase[rb + 192];
        #pragma unroll
        for (int j = 0; j < 4; ++j) {
            const double* wr = wb + (size_t)(kb * 4 + j) * HID;   // uniform -> s_load
            const double v0 = (double)((&f0.x)[j]);
            const double v1 = (double)((&f1.x)[j]);
            const double v2 = (double)((&f2.x)[j]);
            const double v3 = (double)((&f3.x)[j]);
            #pragma unroll
            for (int c = 0; c < 16; ++c) {
                const double w = wr[c];
                a0[c] = fma(v0, w, a0[c]);
                a1[c] = fma(v1, w, a1[c]);
                a2[c] = fma(v2, w, a2[c]);
                a3[c] = fma(v3, w, a3[c]);
            }
        }
    }

    double* dstD = (sel ? Q : P);
    float*  dstF = (sel ? Q32 : P32);
    #pragma unroll
    for (int i = 0; i < 4; ++i) {
        const int gn = n0 + i * 64 + l;
        if (gn >= N_NODES) continue;
        const double* ai = (i == 0) ? a0 : (i == 1) ? a1 : (i == 2) ? a2 : a3;
        double* dst = dstD + (size_t)gn * HID + j0;
        #pragma unroll
        for (int c = 0; c < 16; c += 2)
            *(double2*)(dst + c) = make_double2(ai[c], ai[c + 1]);
        float* dstf = dstF + (size_t)gn * HID + j0;
        #pragma unroll
        for (int c = 0; c < 16; c += 4)
            *(float4*)(dstf + c) = make_float4((float)ai[c], (float)ai[c + 1],
                                               (float)ai[c + 2], (float)ai[c + 3]);
    }
}

// ---------------------------------------------------------------------------
// Kernel 2 (pass A, FUSED): layer-1 fp32 -> h1 bf16 hi/lo (swizzled LDS) ->
// layer-2 bf16x3 MFMA -> layer-3 via padded LDS transpose -> exact-order z
// (fp64 sum of 8 fp32 quarters) -> inline fp64 epilogue on wave 0.
// (round-14 verified, unchanged)
// ---------------------------------------------------------------------------
__global__ __launch_bounds__(512, 4)
void edgeA_kernel(const int*   __restrict__ indices,
                  const float* __restrict__ values,
                  const float* __restrict__ P32,
                  const float* __restrict__ Q32,
                  const float* __restrict__ w1,
                  const float* __restrict__ b1,
                  const short* __restrict__ w2fhi,
                  const short* __restrict__ w2flo,
                  const float* __restrict__ b2,
                  const float* __restrict__ w3,
                  const float* __restrict__ b3,
                  const float* __restrict__ tempr,
                  int*         __restrict__ fcnt,
                  int*         __restrict__ flist,
                  float*       __restrict__ out) {
    __shared__ __align__(16) char smemA[64 * VROW * 4];  // h1 hi|lo ; later vals[64][132]
    __shared__ float zpartS[8][64];
    float* vals = (float*)smemA;

    const int t  = threadIdx.x;
    const int e0 = blockIdx.x * 64;

    // ---- stage h1: fp32 layer-1, split to bf16 hi/lo, swizzled LDS ----
    {
        const int e = t & 63, q = t >> 6;
        const int ge  = e0 + e;
        const int row = indices[ge];
        const int col = indices[NEDGE + ge];
        const float v = values[ge];
        const float* prow = P32 + (size_t)row * HID + q * 16;
        const float* qrow = Q32 + (size_t)col * HID + q * 16;
        const float* w1c  = w1 + (size_t)256 * HID + q * 16;  // uniform -> s_load
        const float* b1f  = b1 + q * 16;
        float h[16];
        #pragma unroll
        for (int i = 0; i < 16; i += 4) {
            float4 p  = *(const float4*)(prow + i);
            float4 qq = *(const float4*)(qrow + i);
            h[i]     = fmaxf(fmaf(v, w1c[i],     p.x + qq.x) + b1f[i],     0.f);
            h[i + 1] = fmaxf(fmaf(v, w1c[i + 1], p.y + qq.y) + b1f[i + 1], 0.f);
            h[i + 2] = fmaxf(fmaf(v, w1c[i + 2], p.z + qq.z) + b1f[i + 2], 0.f);
            h[i + 3] = fmaxf(fmaf(v, w1c[i + 3], p.w + qq.w) + b1f[i + 3], 0.f);
        }
        union { short s[8]; short8 v8; } H0, H1, L0, L1;
        #pragma unroll
        for (int i = 0; i < 8; ++i) {
            const unsigned short hiA = f2bf(h[i]);
            H0.s[i] = (short)hiA;
            L0.s[i] = (short)f2bf(h[i] - bf2f(hiA));
            const unsigned short hiB = f2bf(h[i + 8]);
            H1.s[i] = (short)hiB;
            L1.s[i] = (short)f2bf(h[i + 8] - bf2f(hiB));
        }
        const int a0 = (e * 256 + q * 32) ^ ((e & 7) << 4);
        *(short8*)(smemA + a0)                = H0.v8;
        *(short8*)(smemA + (a0 ^ 16))         = H1.v8;
        *(short8*)(smemA + 16384 + a0)        = L0.v8;
        *(short8*)(smemA + 16384 + (a0 ^ 16)) = L1.v8;
    }
    __syncthreads();

    // ---- layer-2: bf16x3 MFMA, one 32x32 tile per wave, K = 8x16 ----
    const int l  = t & 63;
    const int wv = __builtin_amdgcn_readfirstlane(t >> 6);
    const int jt = wv & 3, et = wv >> 2;
    const int jj = jt * 32 + (l & 31);
    const short* w2h_l = w2fhi + (size_t)(jt * 64 + l) * 8;
    const short* w2l_l = w2flo + (size_t)(jt * 64 + l) * 8;

    f32x16 acc;
    #pragma unroll
    for (int r = 0; r < 16; ++r) acc[r] = 0.f;
    const int eA    = et * 32 + (l & 31);
    const int abase = eA * 256;
    const int aswz  = (eA & 7) << 4;
    const int ah    = (l >> 5) * 16;
    #pragma unroll 2
    for (int s = 0; s < 8; ++s) {
        const int ao = (abase + s * 32 + ah) ^ aswz;
        const short8 ahi = *(const short8*)(smemA + ao);
        const short8 alo = *(const short8*)(smemA + 16384 + ao);
        const short8 bh  = *(const short8*)(w2h_l + s * 2048);
        const short8 bl  = *(const short8*)(w2l_l + s * 2048);
        acc = __builtin_amdgcn_mfma_f32_32x32x16_bf16(ahi, bh, acc, 0, 0, 0);
        acc = __builtin_amdgcn_mfma_f32_32x32x16_bf16(alo, bh, acc, 0, 0, 0);
        acc = __builtin_amdgcn_mfma_f32_32x32x16_bf16(ahi, bl, acc, 0, 0, 0);
    }
    __syncthreads();   // all waves done reading h1 -> safe to overwrite as vals

    // ---- layer-3 part 1: write relu(acc+b2)*w3 to padded vals[64][132] ----
    {
        const float b2j = b2[jj];
        const float w3j = w3[jj];
        #pragma unroll
        for (int r = 0; r < 16; ++r) {
            const int e_loc = (r & 3) + 8 * (r >> 2) + 4 * (l >> 5);
            const int e = et * 32 + e_loc;
            vals[e * VROW + jj] = fmaxf(acc[r] + b2j, 0.f) * w3j;
        }
    }
    __syncthreads();

    // ---- layer-3 part 2: per-thread serial sum of 16 j's (one quarter) ----
    {
        const int e = t & 63, q = t >> 6;
        float sq = 0.f;
        #pragma unroll
        for (int i = 0; i < 4; ++i) {
            const float4 v4 = *(const float4*)(vals + e * VROW + q * 16 + i * 4);
            sq += v4.x; sq += v4.y; sq += v4.z; sq += v4.w;   // jj ascending
        }
        zpartS[q][e] = sq;
    }
    __syncthreads();

    // ---- fused fp64 epilogue: 4 nodes x 16 edges on wave 0 ----
    if (t < 64) {
        double z = (double)b3[0];
        #pragma unroll
        for (int q = 0; q < 8; ++q) z += (double)zpartS[q][t];

        const double T = (double)tempr[0];
        const int base = t & 48;

        // softmax #1
        double m = z;
        #pragma unroll
        for (int d = 1; d < 16; d <<= 1) m = fmax(m, __shfl_xor(m, d));
        const double e1 = exp(z - m);
        double s = 0.0;
        #pragma unroll
        for (int k = 0; k < 16; ++k) s += __shfl(e1, base + k);
        const double pi = e1 / s;

        // hard-concrete, eval path
        const double x  = log(pi + 1e-8) / T;
        double hard = 1.0 / (1.0 + exp(-x));
        hard = fmin(fmax(hard, 0.0), 1.0);

        // softmax #2
        double m2 = hard;
        #pragma unroll
        for (int d = 1; d < 16; d <<= 1) m2 = fmax(m2, __shfl_xor(m2, d));
        const double e2 = exp(hard - m2);
        double s2 = 0.0;
        #pragma unroll
        for (int k = 0; k < 16; ++k) s2 += __shfl(e2, base + k);
        const double y = e2 / s2;

        // rank-8 threshold
        int cgt = 0, ceq = 0;
        #pragma unroll
        for (int j = 0; j < 16; ++j) {
            const double yj = __shfl(y, base + j);
            cgt += (yj > y);
            ceq += (yj == y);
        }
        double cand = (cgt <= 7 && cgt + ceq >= 8) ? y : -1.0e300;
        double thre = cand;
        #pragma unroll
        for (int d = 1; d < 16; d <<= 1) thre = fmax(thre, __shfl_xor(thre, d));

        const double g = (y - thre) + 1e-7;
        out[e0 + t] = (g > 0.0) ? (float)y : 0.0f;

        const bool near = (y != thre) && (fabs(g) < TAU);
        const unsigned long long ball = __ballot(near);
        if ((t & 15) == 0) {
            if ((ball >> base) & 0xFFFFull) {
                const int nid = (e0 >> 4) + (t >> 4);
                const int idx = atomicAdd(fcnt, 1);
                flist[idx] = nid;
            }
        }
    }
}

// ---------------------------------------------------------------------------
// Kernel 3 (pass B): exact fp64 pipeline for flagged nodes, P64/Q64-based
// (round-8 verified version).
// ---------------------------------------------------------------------------
__global__ __launch_bounds__(512, 4)
void edgeB_kernel(const int*   __restrict__ indices,
                  const float* __restrict__ values,
                  const float* __restrict__ tempr,
                  const double* __restrict__ wsd,
                  const double* __restrict__ P,
                  const double* __restrict__ Q,
                  const int*   __restrict__ fcnt,
                  const int*   __restrict__ flist,
                  float* __restrict__ out) {
    __shared__ double h1s[64 * LDSP];
    __shared__ double zpart[8][64];
    __shared__ int nids[4];
    const int t = threadIdx.x;
    const int cnt = *fcnt;

    for (int g0 = blockIdx.x * 4; g0 < cnt; g0 += gridDim.x * 4) {
        if (t < 4) nids[t] = (g0 + t < cnt) ? flist[g0 + t] : -1;
        __syncthreads();

        {
            const int e = t & 63, q = t >> 6;
            const int node = nids[e >> 4];
            double* hdst = &h1s[e * LDSP + q * 16];
            if (node >= 0) {
                const int ge = node * 16 + (e & 15);
                const int row = indices[ge];
                const int col = indices[NEDGE + ge];
                const double v = (double)values[ge];
                const double* prow = P + (size_t)row * HID + q * 16;
                const double* qrow = Q + (size_t)col * HID + q * 16;
                const double* w1c  = wsd + W1D_OFF + (size_t)256 * HID + q * 16;
                const double* b1d  = wsd + B1D_OFF + q * 16;
                #pragma unroll
                for (int i = 0; i < 16; i += 2) {
                    double2 p  = *(const double2*)(prow + i);
                    double2 qq = *(const double2*)(qrow + i);
                    hdst[i]     = fmax(fma(v, w1c[i],     p.x + qq.x) + b1d[i],     0.0);
                    hdst[i + 1] = fmax(fma(v, w1c[i + 1], p.y + qq.y) + b1d[i + 1], 0.0);
                }
            } else {
                #pragma unroll
                for (int i = 0; i < 16; ++i) hdst[i] = 0.0;
            }
        }
        __syncthreads();

        const int l  = t & 63;
        const int wv = __builtin_amdgcn_readfirstlane(t >> 6);
        const int j0 = wv * 16;
        const double* w2b = wsd + W2D_OFF + j0;

        double acc[16];
        #pragma unroll
        for (int c = 0; c < 16; ++c) acc[c] = 0.0;

        const double* hrow = &h1s[l * LDSP];
        for (int k = 0; k < 128; k += 2) {
            const double h0  = hrow[k];
            const double h1v = hrow[k + 1];
            const double* wr0 = w2b + (size_t)k * HID;
            const double* wr1 = wr0 + HID;
            #pragma unroll
            for (int c = 0; c < 16; ++c) acc[c] = fma(h0,  wr0[c], acc[c]);
            #pragma unroll
            for (int c = 0; c < 16; ++c) acc[c] = fma(h1v, wr1[c], acc[c]);
        }

        {
            const double* b2d = wsd + B2D_OFF + j0;
            const double* w3d = wsd + W3D_OFF + j0;
            double part = 0.0;
            #pragma unroll
            for (int c = 0; c < 16; ++c) {
                const double h2 = fmax(acc[c] + b2d[c], 0.0);
                part = fma(h2, w3d[c], part);
            }
            zpart[wv][l] = part;
        }
        __syncthreads();

        if (t < 64) {
            double z = wsd[B3D_OFF];
            #pragma unroll
            for (int w = 0; w < 8; ++w) z += zpart[w][t];

            const double T = (double)tempr[0];
            const int base = t & 48;

            double m = z;
            #pragma unroll
            for (int d = 1; d < 16; d <<= 1) m = fmax(m, __shfl_xor(m, d));
            const double e1 = exp(z - m);
            double s = 0.0;
            #pragma unroll
            for (int k = 0; k < 16; ++k) s += __shfl(e1, base + k);
            const double pi = e1 / s;

            const double x  = log(pi + 1e-8) / T;
            double hard = 1.0 / (1.0 + exp(-x));
            hard = fmin(fmax(hard, 0.0), 1.0);

            double m2 = hard;
            #pragma unroll
            for (int d = 1; d < 16; d <<= 1) m2 = fmax(m2, __shfl_xor(m2, d));
            const double e2 = exp(hard - m2);
            double s2 = 0.0;
            #pragma unroll
            for (int k = 0; k < 16; ++k) s2 += __shfl(e2, base + k);
            const double y = e2 / s2;

            int cgt = 0, ceq = 0;
            #pragma unroll
            for (int j = 0; j < 16; ++j) {
                const double yj = __shfl(y, base + j);
                cgt += (yj > y);
                ceq += (yj == y);
            }
            double cand = (cgt <= 7 && cgt + ceq >= 8) ? y : -1.0e300;
            double thre = cand;
            #pragma unroll
            for (int d = 1; d < 16; d <<= 1) thre = fmax(thre, __shfl_xor(thre, d));

            const double g = (y - thre) + 1e-7;
            const int node = nids[t >> 4];
            if (node >= 0)
                out[node * 16 + (t & 15)] = (g > 0.0) ? (float)y : 0.0f;
        }
        __syncthreads();
    }
}

// ---------------------------------------------------------------------------
extern "C" void kernel_launch(void* const* d_in, const int* in_sizes, int n_in,
                              void* d_out, int out_size, void* d_ws, size_t ws_size,
                              hipStream_t stream) {
    const float* features = (const float*)d_in[0];
    const int*   indices  = (const int*)  d_in[1];
    const float* values   = (const float*)d_in[2];
    const float* tempr    = (const float*)d_in[3];
    const float* w1       = (const float*)d_in[4];
    const float* b1       = (const float*)d_in[5];
    const float* w2       = (const float*)d_in[6];
    const float* b2       = (const float*)d_in[7];
    const float* w3       = (const float*)d_in[8];
    const float* b3       = (const float*)d_in[9];
    float* out = (float*)d_out;

    double* wsd = (double*)d_ws;
    double* P64 = wsd + PQ64_OFF;
    double* Q64 = P64 + (size_t)N_NODES * HID;
    float*  P32 = (float*)(wsd + P32_OFF_D);
    float*  Q32 = P32 + (size_t)N_NODES * HID;
    int*    fcnt  = (int*)(wsd + FLAG_OFF_D);
    int*    flist = fcnt + 1;
    const short* w2fhi = (const short*)(wsd + W2FHI_OFF_D);
    const short* w2flo = (const short*)(wsd + W2FLO_OFF_D);
    float* featT4 = (float*)(wsd + FEATT_OFF_D);

    conv_kernel<<<(NWCONV + 255) / 256, 256, 0, stream>>>(w1, b1, w2, b2, w3, b3, wsd);

    trans_kernel<<<NPAD / 64, 512, 0, stream>>>(features, featT4);

    dim3 g1((N_NODES + 255) / 256, 2);
    pq_kernel<<<g1, 512, 0, stream>>>(featT4, wsd, P64, Q64, P32, Q32);

    edgeA_kernel<<<NEDGE / 64, 512, 0, stream>>>(indices, values, P32, Q32,
                                                 w1, b1, w2fhi, w2flo, b2, w3, b3,
                                                 tempr, fcnt, flist, out);

    edgeB_kernel<<<512, 512, 0, stream>>>(indices, values, tempr, wsd, P64, Q64,
                                          fcnt, flist, out);
}